// Round 11
// baseline (19834.790 us; speedup 1.0000x reference)
//
#include <hip/hip_runtime.h>

// GRU: B=32, T=16384, H=64, CIN=COUT=1.
// d_out = [ out (B*T floats) | states (B*T*H floats) ], fp32.
//
// R10 (third submit -- rounds 9 & 10 both died on infrastructure
// (container failure / acquisition timeout); the kernel has never run).
// R10 = R9 + 2 sequences per block (latency hiding via independent work).
// R9 measured 975 cy/step vs ~600 issue-bound: ~300-400 cy/step is pure
// latency (barrier wait + post-barrier ds_read ~130cy + readlane hazards)
// where the VALU idles. The 32 sequences are independent and weights are
// SHARED -- so each wave runs the matvec for two sequences with the same
// 64 weight VGPRs, interleaved: seq-B's issue fills seq-A's dead windows.
// One lgkm-only barrier serves both updates. 16 blocks x 192 threads.
//   - wave = gate (0=r,1=z,2=n), lane = hidden unit, exactly as R9.
//   - VGPR budget ~105 (weights 64 + 8 accs + 2x seq state + consts):
//     under the 128 tier where the allocator starts spilling (R5-R7).
//   - wave 0 stores seq-A states, wave 1 stores seq-B (fire-and-forget).

#define Bv   32
#define Tv   16384
#define Hv   64

__device__ __forceinline__ float bcast(float v, int k) {
    return __int_as_float(__builtin_amdgcn_readlane(__float_as_int(v), k));
}

// LDS-only barrier: drain lgkmcnt (ghs writes visible), raw s_barrier.
__device__ __forceinline__ void lds_barrier() {
    asm volatile("s_waitcnt lgkmcnt(0)" ::: "memory");
    __builtin_amdgcn_s_barrier();
    asm volatile("" ::: "memory");
}

// 4 h-broadcasts + 4 fmaf into one accumulator chain (one sequence)
#define DOT4(ACC, W, H, K)                                \
    do {                                                  \
        ACC = fmaf(W.x, bcast(H, (K) + 0), ACC);          \
        ACC = fmaf(W.y, bcast(H, (K) + 1), ACC);          \
        ACC = fmaf(W.z, bcast(H, (K) + 2), ACC);          \
        ACC = fmaf(W.w, bcast(H, (K) + 3), ACC);          \
    } while (0)

__global__ __launch_bounds__(192, 1) void gru_scan(
    const float* __restrict__ x,      // [B,T]
    const float* __restrict__ W_ih,   // [192] (CIN=1)
    const float* __restrict__ W_hh,   // [192,64]
    const float* __restrict__ b_ih,   // [192]
    const float* __restrict__ b_hh,   // [192]
    float* __restrict__ states)       // [B,T,64]
{
    const int b0  = blockIdx.x << 1;  // this block owns sequences b0, b0+1
    const int tid = threadIdx.x;
    const int wv  = tid >> 6;         // gate: 0=r, 1=z, 2=n
    const int u   = tid & 63;         // hidden unit (lane)
    const int g   = (wv << 6) + u;    // this thread's gate row

    __shared__ float ghs[2][2][3][Hv];  // 3 KB: [buf][seq][gate][unit]

    const float* xbA = x + (size_t)b0 * Tv;
    const float* xbB = x + (size_t)(b0 + 1) * Tv;
    float*       sbA = states + (size_t)b0 * Tv * Hv;
    float*       sbB = states + (size_t)(b0 + 1) * Tv * Hv;

    // W_hh row g -> 16 named float4 registers (shared by both sequences)
    const float4* Wv = reinterpret_cast<const float4*>(W_hh + (size_t)g * Hv);
    const float4 w0  = Wv[0],  w1  = Wv[1],  w2  = Wv[2],  w3  = Wv[3];
    const float4 w4  = Wv[4],  w5  = Wv[5],  w6  = Wv[6],  w7  = Wv[7];
    const float4 w8  = Wv[8],  w9  = Wv[9],  w10 = Wv[10], w11 = Wv[11];
    const float4 w12 = Wv[12], w13 = Wv[13], w14 = Wv[14], w15 = Wv[15];
    const float bhh_g = b_hh[g];

    // update-phase constants (per lane = unit; identical across the 3 waves)
    const float wih_r = W_ih[u];
    const float wih_z = W_ih[64  + u];
    const float wih_n = W_ih[128 + u];
    const float bih_r = b_ih[u];
    const float bih_z = b_ih[64  + u];
    const float bih_n = b_ih[128 + u];

    float hA = 0.0f, hB = 0.0f;
    float xvA = xbA[u], xvB = xbB[u];   // x chunks for steps [0,64)

    for (int t0 = 0; t0 < Tv; t0 += 64) {
        const int tn = (t0 + 64 < Tv) ? (t0 + 64) : 0;
        const float xvA_next = xbA[tn + u];
        const float xvB_next = xbB[tn + u];

#pragma unroll 2
        for (int tt = 0; tt < 64; ++tt) {
            const int pb = tt & 1;

            // ---- two interleaved matvecs sharing the weight registers ----
            float aA0 = bhh_g, aA1 = 0.0f, aA2 = 0.0f, aA3 = 0.0f;
            float aB0 = bhh_g, aB1 = 0.0f, aB2 = 0.0f, aB3 = 0.0f;
            DOT4(aA0, w0,  hA,  0); DOT4(aB0, w0,  hB,  0);
            DOT4(aA1, w1,  hA,  4); DOT4(aB1, w1,  hB,  4);
            DOT4(aA2, w2,  hA,  8); DOT4(aB2, w2,  hB,  8);
            DOT4(aA3, w3,  hA, 12); DOT4(aB3, w3,  hB, 12);
            DOT4(aA0, w4,  hA, 16); DOT4(aB0, w4,  hB, 16);
            DOT4(aA1, w5,  hA, 20); DOT4(aB1, w5,  hB, 20);
            DOT4(aA2, w6,  hA, 24); DOT4(aB2, w6,  hB, 24);
            DOT4(aA3, w7,  hA, 28); DOT4(aB3, w7,  hB, 28);
            DOT4(aA0, w8,  hA, 32); DOT4(aB0, w8,  hB, 32);
            DOT4(aA1, w9,  hA, 36); DOT4(aB1, w9,  hB, 36);
            DOT4(aA2, w10, hA, 40); DOT4(aB2, w10, hB, 40);
            DOT4(aA3, w11, hA, 44); DOT4(aB3, w11, hB, 44);
            DOT4(aA0, w12, hA, 48); DOT4(aB0, w12, hB, 48);
            DOT4(aA1, w13, hA, 52); DOT4(aB1, w13, hB, 52);
            DOT4(aA2, w14, hA, 56); DOT4(aB2, w14, hB, 56);
            DOT4(aA3, w15, hA, 60); DOT4(aB3, w15, hB, 60);
            ghs[pb][0][wv][u] = (aA0 + aA1) + (aA2 + aA3);
            ghs[pb][1][wv][u] = (aB0 + aB1) + (aB2 + aB3);

            // x-dependent gate inputs (independent of h; fills barrier wait)
            const float xtA  = bcast(xvA, tt);
            const float irA  = fmaf(xtA, wih_r, bih_r);
            const float izA  = fmaf(xtA, wih_z, bih_z);
            const float inA  = fmaf(xtA, wih_n, bih_n);
            const float xtB  = bcast(xvB, tt);
            const float irB  = fmaf(xtB, wih_r, bih_r);
            const float izB  = fmaf(xtB, wih_z, bih_z);
            const float inB  = fmaf(xtB, wih_n, bih_n);

            lds_barrier();            // one lgkm-only barrier for both seqs

            // ---- redundant updates on all 3 waves (lane = unit) ----
            const float grA = ghs[pb][0][0][u];
            const float gzA = ghs[pb][0][1][u];
            const float gnA = ghs[pb][0][2][u];
            const float grB = ghs[pb][1][0][u];
            const float gzB = ghs[pb][1][1][u];
            const float gnB = ghs[pb][1][2][u];

            const float rA = 1.0f / (1.0f + __expf(-(irA + grA)));
            const float zA = 1.0f / (1.0f + __expf(-(izA + gzA)));
            const float aA = fmaf(rA, gnA, inA);
            const float eA = __expf(2.0f * aA);         // tanh via exp
            const float nA = 1.0f - 2.0f / (eA + 1.0f);
            hA = fmaf(zA, hA - nA, nA);

            const float rB = 1.0f / (1.0f + __expf(-(irB + grB)));
            const float zB = 1.0f / (1.0f + __expf(-(izB + gzB)));
            const float aB = fmaf(rB, gnB, inB);
            const float eB = __expf(2.0f * aB);
            const float nB = 1.0f - 2.0f / (eB + 1.0f);
            hB = fmaf(zB, hB - nB, nB);

            // fire-and-forget stores, one per wave
            if (wv == 0)      sbA[(size_t)(t0 + tt) * Hv + u] = hA;
            else if (wv == 1) sbB[(size_t)(t0 + tt) * Hv + u] = hB;
        }
        xvA = xvA_next;
        xvB = xvB_next;
    }
}

// out[i] = states[i,:] . W_out + b_out + x[i],  i in [0, B*T)
__global__ __launch_bounds__(256) void gru_head(
    const float* __restrict__ x,
    const float* __restrict__ states,
    const float* __restrict__ W_out,   // [64]
    const float* __restrict__ b_out,   // [1]
    float* __restrict__ out)
{
    __shared__ float wsm[Hv];
    if (threadIdx.x < Hv) wsm[threadIdx.x] = W_out[threadIdx.x];
    __syncthreads();

    const int i = blockIdx.x * blockDim.x + threadIdx.x;
    if (i >= Bv * Tv) return;

    const float4* s4 = reinterpret_cast<const float4*>(states + (size_t)i * Hv);
    float acc = 0.0f;
#pragma unroll
    for (int k = 0; k < Hv / 4; ++k) {
        const float4 v = s4[k];
        acc = fmaf(v.x, wsm[4*k+0], acc);
        acc = fmaf(v.y, wsm[4*k+1], acc);
        acc = fmaf(v.z, wsm[4*k+2], acc);
        acc = fmaf(v.w, wsm[4*k+3], acc);
    }
    out[i] = acc + b_out[0] + x[i];
}

extern "C" void kernel_launch(void* const* d_in, const int* in_sizes, int n_in,
                              void* d_out, int out_size, void* d_ws, size_t ws_size,
                              hipStream_t stream) {
    const float* x     = (const float*)d_in[0];   // [B,T,1]
    const float* W_ih  = (const float*)d_in[1];   // [192,1]
    const float* W_hh  = (const float*)d_in[2];   // [192,64]
    const float* b_ih  = (const float*)d_in[3];   // [192]
    const float* b_hh  = (const float*)d_in[4];   // [192]
    const float* W_out = (const float*)d_in[5];   // [1,64]
    const float* b_out = (const float*)d_in[6];   // [1]

    float* out    = (float*)d_out;                // [B*T]
    float* states = out + (size_t)Bv * Tv;        // [B*T*H]

    gru_scan<<<Bv / 2, 192, 0, stream>>>(x, W_ih, W_hh, b_ih, b_hh, states);
    gru_head<<<(Bv * Tv + 255) / 256, 256, 0, stream>>>(x, states, W_out, b_out, out);
}

// Round 14
// 9652.985 us; speedup vs baseline: 2.0548x; 2.0548x over previous
//
#include <hip/hip_runtime.h>

// GRU: B=32, T=16384, H=64, CIN=COUT=1.
// d_out = [ out (B*T floats) | states (B*T*H floats) ], fp32.
//
// R11 (third submit -- rounds 12 & 13 both died with GPUAcquisitionTimeout;
// this kernel has never executed).
// R11 = R9 skeleton + W_hh streamed from LDS each step (transposed k-packed
// layout, conflict-free ds_read_b128).
// R10 post-mortem: VGPR_Count=48 in BOTH R9 and R10 -- the 16 float4 weights
// (64 VGPRs) were NEVER register-resident in any version; every step reloads
// W_hh from cache with 256B-lane-stride (uncoalesced) global loads. R10's
// 2-seq body under the same 48-VGPR budget serialized those loads (~1800cy
// stall/pair, 19.8ms). The allocator will not give us weight residency
// (R5/R6/R7 exhausted opacity barriers + waves_per_eu pinning).
// So: embrace per-step streaming, but from LDS with an optimal layout:
//   - lw[kq][g] float4 = W_hh[g][4kq..4kq+3]  (48 KB). Per wave per step:
//     16 ds_read_b128 at lw[kq][wv*64+u] -> 64 lanes x 16B CONTIGUOUS
//     (m134-optimal, zero conflicts; R8's failure was a conflicted layout
//     on 1 wave: 48 serialized reads, 8-way conflicts).
//   - staging writes lw[kq][tid]: wave w writes exactly the rows it later
//     reads (g==tid) -> same-wave DS ordering, no barrier needed.
//   - opaque off=0 per iteration (R8-proven) stops LICM from hoisting the
//     loop-invariant reads and re-creating the spill.
//   - everything else is R9: wave=gate, lane=unit, 64-readlane h-crossbar,
//     1 lgkm-only barrier/step, double-buffered ghs, fire-and-forget stores.

#define Bv   32
#define Tv   16384
#define Hv   64

__device__ __forceinline__ float bcast(float v, int k) {
    return __int_as_float(__builtin_amdgcn_readlane(__float_as_int(v), k));
}

// LDS-only barrier: drain lgkmcnt (ghs writes visible), raw s_barrier.
__device__ __forceinline__ void lds_barrier() {
    asm volatile("s_waitcnt lgkmcnt(0)" ::: "memory");
    __builtin_amdgcn_s_barrier();
    asm volatile("" ::: "memory");
}

// 4 h-broadcasts + 4 fmaf into one accumulator chain
#define DOT4(ACC, W, K)                                   \
    do {                                                  \
        ACC = fmaf(W.x, bcast(h, (K) + 0), ACC);          \
        ACC = fmaf(W.y, bcast(h, (K) + 1), ACC);          \
        ACC = fmaf(W.z, bcast(h, (K) + 2), ACC);          \
        ACC = fmaf(W.w, bcast(h, (K) + 3), ACC);          \
    } while (0)

__global__ __launch_bounds__(192, 1) void gru_scan(
    const float* __restrict__ x,      // [B,T]
    const float* __restrict__ W_ih,   // [192] (CIN=1)
    const float* __restrict__ W_hh,   // [192,64]
    const float* __restrict__ b_ih,   // [192]
    const float* __restrict__ b_hh,   // [192]
    float* __restrict__ states)       // [B,T,64]
{
    const int b   = blockIdx.x;
    const int tid = threadIdx.x;
    const int wv  = tid >> 6;         // gate: 0=r, 1=z, 2=n
    const int u   = tid & 63;         // hidden unit (lane)
    const int g   = tid;              // gate row == tid (wv*64+u)

    __shared__ float4 lw[16][192];    // 48 KB: lw[kq][g] = W_hh[g][4kq..4kq+3]
    __shared__ float  ghs[2][3][Hv];  // 1.5 KB double-buffered gate exchange

    const float* xb = x + (size_t)b * Tv;
    float*       sb = states + (size_t)b * Tv * Hv;

    // ---- one-time stage: W_hh -> LDS, k-packed transpose ----
    // thread tid writes rows g==tid for all kq: each wave writes exactly the
    // rows it will read -> same-wave DS ordering, no barrier required.
    {
        const float4* Wg4 = reinterpret_cast<const float4*>(W_hh);
        for (int kq = 0; kq < 16; ++kq)
            lw[kq][tid] = Wg4[(size_t)tid * 16 + kq];
    }

    const float bhh_g = b_hh[g];

    // update-phase constants (per lane = unit; identical across the 3 waves)
    const float wih_r = W_ih[u];
    const float wih_z = W_ih[64  + u];
    const float wih_n = W_ih[128 + u];
    const float bih_r = b_ih[u];
    const float bih_z = b_ih[64  + u];
    const float bih_n = b_ih[128 + u];

    float h  = 0.0f;
    float xv = xb[u];                 // x chunk for steps [0,64)

    for (int t0 = 0; t0 < Tv; t0 += 64) {
        // prefetch next x chunk (safe dummy index on the last chunk)
        const int tn = (t0 + 64 < Tv) ? (t0 + 64) : 0;
        const float xv_next = xb[tn + u];

#pragma unroll 2
        for (int tt = 0; tt < 64; ++tt) {
            const int pb = tt & 1;

            // opaque zero index: blocks LICM/CSE of the weight reads
            int off = 0;
            asm volatile("" : "+v"(off));

            // ---- matvec: own gate row . h ----
            // 16 conflict-free ds_read_b128 (contiguous across lanes),
            // interleaved with the 64-readlane crossbar; 4 indep chains.
            float a0 = bhh_g, a1 = 0.0f, a2 = 0.0f, a3 = 0.0f;
            { const float4 w = lw[ 0][g + off]; DOT4(a0, w,  0); }
            { const float4 w = lw[ 1][g + off]; DOT4(a1, w,  4); }
            { const float4 w = lw[ 2][g + off]; DOT4(a2, w,  8); }
            { const float4 w = lw[ 3][g + off]; DOT4(a3, w, 12); }
            { const float4 w = lw[ 4][g + off]; DOT4(a0, w, 16); }
            { const float4 w = lw[ 5][g + off]; DOT4(a1, w, 20); }
            { const float4 w = lw[ 6][g + off]; DOT4(a2, w, 24); }
            { const float4 w = lw[ 7][g + off]; DOT4(a3, w, 28); }
            { const float4 w = lw[ 8][g + off]; DOT4(a0, w, 32); }
            { const float4 w = lw[ 9][g + off]; DOT4(a1, w, 36); }
            { const float4 w = lw[10][g + off]; DOT4(a2, w, 40); }
            { const float4 w = lw[11][g + off]; DOT4(a3, w, 44); }
            { const float4 w = lw[12][g + off]; DOT4(a0, w, 48); }
            { const float4 w = lw[13][g + off]; DOT4(a1, w, 52); }
            { const float4 w = lw[14][g + off]; DOT4(a2, w, 56); }
            { const float4 w = lw[15][g + off]; DOT4(a3, w, 60); }
            ghs[pb][wv][u] = (a0 + a1) + (a2 + a3);

            // x-dependent gate inputs (independent of h; fills barrier wait)
            const float xt  = bcast(xv, tt);
            const float ir  = fmaf(xt, wih_r, bih_r);
            const float iz  = fmaf(xt, wih_z, bih_z);
            const float in_ = fmaf(xt, wih_n, bih_n);

            lds_barrier();            // the only barrier per step (lgkm-only)

            // ---- redundant h-update on all 3 waves (lane = unit) ----
            const float gr = ghs[pb][0][u];
            const float gz = ghs[pb][1][u];
            const float gn = ghs[pb][2][u];

            const float r  = 1.0f / (1.0f + __expf(-(ir + gr)));
            const float z  = 1.0f / (1.0f + __expf(-(iz + gz)));
            const float a  = fmaf(r, gn, in_);
            const float e  = __expf(2.0f * a);          // tanh(a) = 1 - 2/(e+1)
            const float n  = 1.0f - 2.0f / (e + 1.0f);
            h = fmaf(z, h - n, n);                      // (1-z)*n + z*h

            if (wv == 0) sb[(size_t)(t0 + tt) * Hv + u] = h;  // fire-and-forget
        }
        xv = xv_next;
    }
}

// out[i] = states[i,:] . W_out + b_out + x[i],  i in [0, B*T)
__global__ __launch_bounds__(256) void gru_head(
    const float* __restrict__ x,
    const float* __restrict__ states,
    const float* __restrict__ W_out,   // [64]
    const float* __restrict__ b_out,   // [1]
    float* __restrict__ out)
{
    __shared__ float wsm[Hv];
    if (threadIdx.x < Hv) wsm[threadIdx.x] = W_out[threadIdx.x];
    __syncthreads();

    const int i = blockIdx.x * blockDim.x + threadIdx.x;
    if (i >= Bv * Tv) return;

    const float4* s4 = reinterpret_cast<const float4*>(states + (size_t)i * Hv);
    float acc = 0.0f;
#pragma unroll
    for (int k = 0; k < Hv / 4; ++k) {
        const float4 v = s4[k];
        acc = fmaf(v.x, wsm[4*k+0], acc);
        acc = fmaf(v.y, wsm[4*k+1], acc);
        acc = fmaf(v.z, wsm[4*k+2], acc);
        acc = fmaf(v.w, wsm[4*k+3], acc);
    }
    out[i] = acc + b_out[0] + x[i];
}

extern "C" void kernel_launch(void* const* d_in, const int* in_sizes, int n_in,
                              void* d_out, int out_size, void* d_ws, size_t ws_size,
                              hipStream_t stream) {
    const float* x     = (const float*)d_in[0];   // [B,T,1]
    const float* W_ih  = (const float*)d_in[1];   // [192,1]
    const float* W_hh  = (const float*)d_in[2];   // [192,64]
    const float* b_ih  = (const float*)d_in[3];   // [192]
    const float* b_hh  = (const float*)d_in[4];   // [192]
    const float* W_out = (const float*)d_in[5];   // [1,64]
    const float* b_out = (const float*)d_in[6];   // [1]

    float* out    = (float*)d_out;                // [B*T]
    float* states = out + (size_t)Bv * Tv;        // [B*T*H]

    gru_scan<<<Bv, 192, 0, stream>>>(x, W_ih, W_hh, b_ih, b_hh, states);
    gru_head<<<(Bv * Tv + 255) / 256, 256, 0, stream>>>(x, states, W_out, b_out, out);
}

// Round 17
// 8250.740 us; speedup vs baseline: 2.4040x; 1.1700x over previous
//
#include <hip/hip_runtime.h>

// GRU: B=32, T=16384, H=64, CIN=COUT=1.
// d_out = [ out (B*T floats) | states (B*T*H floats) ], fp32.
//
// R13 = R12 with the fma fixed: gfx950 VALU v_fma_f32 can NOT read an AGPR
// source (R12 compile error: "v_fma_f32 v6, a0, s10, v6 -- invalid
// operand"). AGPRs are VALU-readable only via v_accvgpr_read_b32.
//   - weights stay pinned in 64 AGPRs/lane (the "=a" stash compiled fine);
//     per use: volatile v_accvgpr_read_b32 (volatile so the reads can't be
//     LICM-hoisted, which would recreate the R5-R7 64-live-VGPR spill),
//     then plain readlane + fmaf.
//   - per-step weight MEMORY traffic: zero (vs R9's 48KB L2 re-stream,
//     the measured 975cy/step floor; vs R11's 576cy LDS pipe floor).
//   - issue budget/step: 64 accvgpr_read + 64 readlane + 64 fmaf ~ 384cy
//     + ~300cy ghs/barrier/update chain -> ~700-800cy (R9: 975).
//   - everything else exactly R9: wave=gate, lane=unit, ghs exchange,
//     one lgkm-only barrier, fire-and-forget stores.

#define Bv   32
#define Tv   16384
#define Hv   64

// LDS-only barrier: drain lgkmcnt (ghs writes visible), raw s_barrier.
__device__ __forceinline__ void lds_barrier() {
    asm volatile("s_waitcnt lgkmcnt(0)" ::: "memory");
    __builtin_amdgcn_s_barrier();
    asm volatile("" ::: "memory");
}

__device__ __forceinline__ float bcastf(float v, int k) {
    return __int_as_float(__builtin_amdgcn_readlane(__float_as_int(v), k));
}

// declare one float4-worth of AGPR-resident weights
#define DECLW(i) float aw##i##x, aw##i##y, aw##i##z, aw##i##w
// stash a loaded float4 into those AGPRs (opaque: no remat, no heuristic spill)
#define STASH(i, V)                                                          \
    asm("v_accvgpr_write_b32 %0, %1" : "=a"(aw##i##x) : "v"((V).x));         \
    asm("v_accvgpr_write_b32 %0, %1" : "=a"(aw##i##y) : "v"((V).y));         \
    asm("v_accvgpr_write_b32 %0, %1" : "=a"(aw##i##z) : "v"((V).z));         \
    asm("v_accvgpr_write_b32 %0, %1" : "=a"(aw##i##w) : "v"((V).w))
// pull one AGPR back to a VGPR. volatile: must not be hoisted out of the
// step loop (hoisting = 64 live VGPRs = the R5-R7 spill death).
#define ARD(DST, SRC)                                                        \
    asm volatile("v_accvgpr_read_b32 %0, %1" : "=v"(DST) : "a"(SRC))
// one float4 group: 4 AGPR reads, then 4 x (readlane bcast + fmaf)
#define DOT4A(ACC, P, K)                                                     \
    do {                                                                     \
        float wx_, wy_, wz_, ww_;                                            \
        ARD(wx_, P##x); ARD(wy_, P##y); ARD(wz_, P##z); ARD(ww_, P##w);      \
        ACC = fmaf(wx_, bcastf(h, (K) + 0), ACC);                            \
        ACC = fmaf(wy_, bcastf(h, (K) + 1), ACC);                            \
        ACC = fmaf(wz_, bcastf(h, (K) + 2), ACC);                            \
        ACC = fmaf(ww_, bcastf(h, (K) + 3), ACC);                            \
    } while (0)

__global__ __launch_bounds__(192, 1) void gru_scan(
    const float* __restrict__ x,      // [B,T]
    const float* __restrict__ W_ih,   // [192] (CIN=1)
    const float* __restrict__ W_hh,   // [192,64]
    const float* __restrict__ b_ih,   // [192]
    const float* __restrict__ b_hh,   // [192]
    float* __restrict__ states)       // [B,T,64]
{
    const int b   = blockIdx.x;
    const int tid = threadIdx.x;
    const int wv  = tid >> 6;         // gate: 0=r, 1=z, 2=n
    const int u   = tid & 63;         // hidden unit (lane)
    const int g   = tid;              // gate row == tid (wv*64+u)

    __shared__ float ghs[2][3][Hv];   // 1.5 KB double-buffered gate exchange

    const float* xb = x + (size_t)b * Tv;
    float*       sb = states + (size_t)b * Tv * Hv;

    // ---- one-time: W_hh row g -> 64 AGPRs per lane ----
    DECLW(0);  DECLW(1);  DECLW(2);  DECLW(3);
    DECLW(4);  DECLW(5);  DECLW(6);  DECLW(7);
    DECLW(8);  DECLW(9);  DECLW(10); DECLW(11);
    DECLW(12); DECLW(13); DECLW(14); DECLW(15);
    {
        const float4* Wv = reinterpret_cast<const float4*>(W_hh + (size_t)g * Hv);
        float4 t;
        t = Wv[0];  STASH(0, t);   t = Wv[1];  STASH(1, t);
        t = Wv[2];  STASH(2, t);   t = Wv[3];  STASH(3, t);
        t = Wv[4];  STASH(4, t);   t = Wv[5];  STASH(5, t);
        t = Wv[6];  STASH(6, t);   t = Wv[7];  STASH(7, t);
        t = Wv[8];  STASH(8, t);   t = Wv[9];  STASH(9, t);
        t = Wv[10]; STASH(10, t);  t = Wv[11]; STASH(11, t);
        t = Wv[12]; STASH(12, t);  t = Wv[13]; STASH(13, t);
        t = Wv[14]; STASH(14, t);  t = Wv[15]; STASH(15, t);
    }

    const float bhh_g = b_hh[g];

    // update-phase constants (per lane = unit; identical across the 3 waves)
    const float wih_r = W_ih[u];
    const float wih_z = W_ih[64  + u];
    const float wih_n = W_ih[128 + u];
    const float bih_r = b_ih[u];
    const float bih_z = b_ih[64  + u];
    const float bih_n = b_ih[128 + u];

    float h  = 0.0f;
    float xv = xb[u];                 // x chunk for steps [0,64)

    for (int t0 = 0; t0 < Tv; t0 += 64) {
        // prefetch next x chunk (safe dummy index on the last chunk)
        const int tn = (t0 + 64 < Tv) ? (t0 + 64) : 0;
        const float xv_next = xb[tn + u];

#pragma unroll 2
        for (int tt = 0; tt < 64; ++tt) {
            const int pb = tt & 1;

            // ---- matvec: own gate row (AGPR-pinned) . h (readlane) ----
            // 4 independent accumulator chains.
            float a0 = bhh_g, a1 = 0.0f, a2 = 0.0f, a3 = 0.0f;
            DOT4A(a0, aw0,   0); DOT4A(a1, aw1,   4);
            DOT4A(a2, aw2,   8); DOT4A(a3, aw3,  12);
            DOT4A(a0, aw4,  16); DOT4A(a1, aw5,  20);
            DOT4A(a2, aw6,  24); DOT4A(a3, aw7,  28);
            DOT4A(a0, aw8,  32); DOT4A(a1, aw9,  36);
            DOT4A(a2, aw10, 40); DOT4A(a3, aw11, 44);
            DOT4A(a0, aw12, 48); DOT4A(a1, aw13, 52);
            DOT4A(a2, aw14, 56); DOT4A(a3, aw15, 60);
            ghs[pb][wv][u] = (a0 + a1) + (a2 + a3);

            // x-dependent gate inputs (independent of h; fills barrier wait)
            const float xt  = bcastf(xv, tt);
            const float ir  = fmaf(xt, wih_r, bih_r);
            const float iz  = fmaf(xt, wih_z, bih_z);
            const float in_ = fmaf(xt, wih_n, bih_n);

            lds_barrier();            // the only barrier per step (lgkm-only)

            // ---- redundant h-update on all 3 waves (lane = unit) ----
            const float gr = ghs[pb][0][u];
            const float gz = ghs[pb][1][u];
            const float gn = ghs[pb][2][u];

            const float r  = 1.0f / (1.0f + __expf(-(ir + gr)));
            const float z  = 1.0f / (1.0f + __expf(-(iz + gz)));
            const float a  = fmaf(r, gn, in_);
            const float e  = __expf(2.0f * a);          // tanh(a) = 1 - 2/(e+1)
            const float n  = 1.0f - 2.0f / (e + 1.0f);
            h = fmaf(z, h - n, n);                      // (1-z)*n + z*h

            if (wv == 0) sb[(size_t)(t0 + tt) * Hv + u] = h;  // fire-and-forget
        }
        xv = xv_next;
    }
}

// out[i] = states[i,:] . W_out + b_out + x[i],  i in [0, B*T)
__global__ __launch_bounds__(256) void gru_head(
    const float* __restrict__ x,
    const float* __restrict__ states,
    const float* __restrict__ W_out,   // [64]
    const float* __restrict__ b_out,   // [1]
    float* __restrict__ out)
{
    __shared__ float wsm[Hv];
    if (threadIdx.x < Hv) wsm[threadIdx.x] = W_out[threadIdx.x];
    __syncthreads();

    const int i = blockIdx.x * blockDim.x + threadIdx.x;
    if (i >= Bv * Tv) return;

    const float4* s4 = reinterpret_cast<const float4*>(states + (size_t)i * Hv);
    float acc = 0.0f;
#pragma unroll
    for (int k = 0; k < Hv / 4; ++k) {
        const float4 v = s4[k];
        acc = fmaf(v.x, wsm[4*k+0], acc);
        acc = fmaf(v.y, wsm[4*k+1], acc);
        acc = fmaf(v.z, wsm[4*k+2], acc);
        acc = fmaf(v.w, wsm[4*k+3], acc);
    }
    out[i] = acc + b_out[0] + x[i];
}

extern "C" void kernel_launch(void* const* d_in, const int* in_sizes, int n_in,
                              void* d_out, int out_size, void* d_ws, size_t ws_size,
                              hipStream_t stream) {
    const float* x     = (const float*)d_in[0];   // [B,T,1]
    const float* W_ih  = (const float*)d_in[1];   // [192,1]
    const float* W_hh  = (const float*)d_in[2];   // [192,64]
    const float* b_ih  = (const float*)d_in[3];   // [192]
    const float* b_hh  = (const float*)d_in[4];   // [192]
    const float* W_out = (const float*)d_in[5];   // [1,64]
    const float* b_out = (const float*)d_in[6];   // [1]

    float* out    = (float*)d_out;                // [B*T]
    float* states = out + (size_t)Bv * Tv;        // [B*T*H]

    gru_scan<<<Bv, 192, 0, stream>>>(x, W_ih, W_hh, b_ih, b_hh, states);
    gru_head<<<(Bv * Tv + 255) / 256, 256, 0, stream>>>(x, states, W_out, b_out, out);
}